// Round 1
// baseline (1755.871 us; speedup 1.0000x reference)
//
#include <hip/hip_runtime.h>

// ---- problem constants ----
#define B_ 8
#define T_ 1024
#define C_ 384
#define L_ 8
#define H_ 16
#define D_ 24
#define F_ 1536
#define M_ 8192   // B_*T_

using bf16x8 = __attribute__((ext_vector_type(8))) __bf16;
using f32x4  = __attribute__((ext_vector_type(4))) float;

__device__ __forceinline__ ushort f2b(float f) {
  union { float f; unsigned u; } cv; cv.f = f;
  unsigned u = cv.u;
  return (ushort)((u + 0x7FFFu + ((u >> 16) & 1u)) >> 16);  // RNE
}

// ---------------- embed: x = idx + pos ----------------
__global__ __launch_bounds__(256) void k_embed(const float* __restrict__ idx,
                                               const float* __restrict__ pos,
                                               float* __restrict__ x) {
  long i4 = ((long)blockIdx.x * 256 + threadIdx.x) * 4;
  float4 a = *(const float4*)(idx + i4);
  long p = i4 % (long)(T_ * C_);
  float4 b = *(const float4*)(pos + p);
  a.x += b.x; a.y += b.y; a.z += b.z; a.w += b.w;
  *(float4*)(x + i4) = a;
}

// ---------------- layernorm (fp32 in) -> bf16 out ----------------
// one wave per row; 384 = 64 lanes * 6
__global__ __launch_bounds__(256) void k_ln(const float* __restrict__ x,
                                            const float* __restrict__ g,
                                            const float* __restrict__ b,
                                            ushort* __restrict__ out) {
  int row  = blockIdx.x * 4 + (threadIdx.x >> 6);
  int lane = threadIdx.x & 63;
  const float* xr = x + (long)row * C_;
  float v[6]; float sum = 0.f;
#pragma unroll
  for (int i = 0; i < 3; ++i) {
    float2 t = *(const float2*)(xr + 2*(lane + 64*i));
    v[2*i] = t.x; v[2*i+1] = t.y; sum += t.x + t.y;
  }
#pragma unroll
  for (int m = 1; m < 64; m <<= 1) sum += __shfl_xor(sum, m);
  float mean = sum * (1.f / C_);
  float vs = 0.f;
#pragma unroll
  for (int i = 0; i < 6; ++i) { float d = v[i] - mean; vs += d * d; }
#pragma unroll
  for (int m = 1; m < 64; m <<= 1) vs += __shfl_xor(vs, m);
  float rstd = rsqrtf(vs * (1.f / C_) + 1e-5f);
  ushort* orow = out + (long)row * C_;
#pragma unroll
  for (int i = 0; i < 3; ++i) {
    int c = 2*(lane + 64*i);
    float2 gg = *(const float2*)(g + c);
    float2 bb = *(const float2*)(b + c);
    ushort2 w;
    w.x = f2b((v[2*i]   - mean) * rstd * gg.x + bb.x);
    w.y = f2b((v[2*i+1] - mean) * rstd * gg.y + bb.y);
    *(ushort2*)(orow + c) = w;
  }
}

// ---------------- final layernorm + relu -> fp32 d_out ----------------
__global__ __launch_bounds__(256) void k_lnf(const float* __restrict__ x,
                                             const float* __restrict__ g,
                                             const float* __restrict__ b,
                                             float* __restrict__ out) {
  int row  = blockIdx.x * 4 + (threadIdx.x >> 6);
  int lane = threadIdx.x & 63;
  const float* xr = x + (long)row * C_;
  float v[6]; float sum = 0.f;
#pragma unroll
  for (int i = 0; i < 3; ++i) {
    float2 t = *(const float2*)(xr + 2*(lane + 64*i));
    v[2*i] = t.x; v[2*i+1] = t.y; sum += t.x + t.y;
  }
#pragma unroll
  for (int m = 1; m < 64; m <<= 1) sum += __shfl_xor(sum, m);
  float mean = sum * (1.f / C_);
  float vs = 0.f;
#pragma unroll
  for (int i = 0; i < 6; ++i) { float d = v[i] - mean; vs += d * d; }
#pragma unroll
  for (int m = 1; m < 64; m <<= 1) vs += __shfl_xor(vs, m);
  float rstd = rsqrtf(vs * (1.f / C_) + 1e-5f);
  float* orow = out + (long)row * C_;
#pragma unroll
  for (int i = 0; i < 3; ++i) {
    int c = 2*(lane + 64*i);
    float2 gg = *(const float2*)(g + c);
    float2 bb = *(const float2*)(b + c);
    float2 w;
    w.x = fmaxf((v[2*i]   - mean) * rstd * gg.x + bb.x, 0.f);
    w.y = fmaxf((v[2*i+1] - mean) * rstd * gg.y + bb.y, 0.f);
    *(float2*)(orow + c) = w;
  }
}

// ---------------- weight transpose+cast kernels ----------------
// qkv: src = W{q,k,v} [L*H batches of [C][D]] -> dst WqkvT[l] rows (which*384+h*24+d)[c]
__global__ __launch_bounds__(256) void k_trans_qkv(const float* __restrict__ src,
                                                   ushort* __restrict__ dst, int which) {
  __shared__ float tile[32][33];
  int z = blockIdx.z;            // l*H + h
  int l = z >> 4, hh = z & 15;
  const float* sb = src + (long)z * C_ * D_;
  ushort* db = dst + (long)l * (3*C_) * C_ + (long)(which * C_ + hh * D_) * C_;
  int r0 = blockIdx.y * 32;      // c dim
  int tx = threadIdx.x & 31, ty = threadIdx.x >> 5;
#pragma unroll
  for (int i = 0; i < 32; i += 8)
    tile[ty + i][tx] = (tx < D_) ? sb[(long)(r0 + ty + i) * D_ + tx] : 0.f;
  __syncthreads();
#pragma unroll
  for (int i = 0; i < 32; i += 8) {
    int s = ty + i, r = r0 + tx;
    if (s < D_) db[(long)s * C_ + r] = f2b(tile[tx][ty + i]);
  }
}

// generic: src [batch][R][S] fp32 -> dst [batch][S][R] bf16
__global__ __launch_bounds__(256) void k_trans_w(const float* __restrict__ src,
                                                 ushort* __restrict__ dst, int R, int S) {
  __shared__ float tile[32][33];
  const float* sb = src + (long)blockIdx.z * R * S;
  ushort* db = dst + (long)blockIdx.z * R * S;
  int r0 = blockIdx.y * 32, s0 = blockIdx.x * 32;
  int tx = threadIdx.x & 31, ty = threadIdx.x >> 5;
#pragma unroll
  for (int i = 0; i < 32; i += 8) {
    int r = r0 + ty + i, s = s0 + tx;
    tile[ty + i][tx] = (r < R && s < S) ? sb[(long)r * S + s] : 0.f;
  }
  __syncthreads();
#pragma unroll
  for (int i = 0; i < 32; i += 8) {
    int s = s0 + ty + i, r = r0 + tx;
    if (s < S && r < R) db[(long)s * R + r] = f2b(tile[tx][ty + i]);
  }
}

// ---------------- GEMM: A[M,K]bf16 @ Bt[N,K]bf16^T -> out[M,N] ----------------
// 128x128 tile, BK=64, 4 waves (each 64x64), mfma 16x16x32, XOR-swizzled LDS (T2)
__global__ __launch_bounds__(256) void k_gemm(const ushort* __restrict__ A, int lda,
                                              const ushort* __restrict__ Bt, int ldb,
                                              const float* __restrict__ bias,
                                              const float* resid,
                                              float* outF,
                                              ushort* outB,
                                              int N, int K, int relu) {
  __shared__ ushort As[128 * 64];
  __shared__ ushort Bs[128 * 64];
  int m0 = blockIdx.y * 128, n0 = blockIdx.x * 128;
  int tid = threadIdx.x, lane = tid & 63, wid = tid >> 6;
  int wr = (wid >> 1) * 64, wc = (wid & 1) * 64;
  int g = lane >> 4, q = lane & 15;
  f32x4 acc[4][4] = {};

  for (int k0 = 0; k0 < K; k0 += 64) {
    __syncthreads();
#pragma unroll
    for (int it = 0; it < 4; ++it) {
      int idx = tid + it * 256;
      int r = idx >> 3, c8 = (idx & 7) << 3;
      int sw = ((r * 64 + c8) * 2) ^ ((r & 7) << 4);
      uint4 av = *(const uint4*)(A + (long)(m0 + r) * lda + k0 + c8);
      *(uint4*)((char*)As + sw) = av;
      uint4 bv = *(const uint4*)(Bt + (long)(n0 + r) * ldb + k0 + c8);
      *(uint4*)((char*)Bs + sw) = bv;
    }
    __syncthreads();
#pragma unroll
    for (int kk = 0; kk < 2; ++kk) {
      bf16x8 af[4], bfr[4];
#pragma unroll
      for (int mi = 0; mi < 4; ++mi) {
        int row = wr + mi * 16 + q;
        int byt = ((row * 64 + kk * 32 + g * 8) * 2) ^ ((row & 7) << 4);
        af[mi] = *(const bf16x8*)((const char*)As + byt);
      }
#pragma unroll
      for (int ni = 0; ni < 4; ++ni) {
        int row = wc + ni * 16 + q;
        int byt = ((row * 64 + kk * 32 + g * 8) * 2) ^ ((row & 7) << 4);
        bfr[ni] = *(const bf16x8*)((const char*)Bs + byt);
      }
#pragma unroll
      for (int mi = 0; mi < 4; ++mi)
#pragma unroll
        for (int ni = 0; ni < 4; ++ni)
          acc[mi][ni] = __builtin_amdgcn_mfma_f32_16x16x32_bf16(af[mi], bfr[ni], acc[mi][ni], 0, 0, 0);
    }
  }
  // epilogue: D layout col=lane&15, row=4*(lane>>4)+j  [m89-verified]
#pragma unroll
  for (int mi = 0; mi < 4; ++mi)
#pragma unroll
    for (int ni = 0; ni < 4; ++ni) {
      int rb = m0 + wr + mi * 16 + g * 4;
      int cc = n0 + wc + ni * 16 + q;
      float bv = bias ? bias[cc] : 0.f;
#pragma unroll
      for (int j = 0; j < 4; ++j) {
        long off = (long)(rb + j) * N + cc;
        float val = acc[mi][ni][j] + bv;
        if (resid) val += resid[off];
        if (relu)  val = fmaxf(val, 0.f);
        if (outF)  outF[off] = val;
        if (outB)  outB[off] = f2b(val);
      }
    }
}

// ---------------- flash attention (no-max online softmax) ----------------
// block = (b,h, 64 q rows); 4 waves, each 16 q rows. qkv row stride 1152:
// q at col h*24, k at 384+h*24, v at 768+h*24. Scores tiny (|S*scale| < ~1) so
// exp without max-subtraction is safe; track only running row-sum.
__global__ __launch_bounds__(256) void k_attn(const ushort* __restrict__ qkv,
                                              ushort* __restrict__ o) {
  __shared__ ushort Qs[64 * 40];    // [t][d], d padded 24->32 (cols 32..39 unused)
  __shared__ ushort Ks[128 * 40];   // [s][d]
  __shared__ ushort Vts[32 * 136];  // [d][s], rows 24..31 zero
  __shared__ ushort Ps[64 * 136];   // [t][s] bf16 P, per-wave 16-row slices

  int t0 = blockIdx.x * 64;
  int bh = blockIdx.y; int b = bh >> 4, hh = bh & 15;
  int tid = threadIdx.x, lane = tid & 63, w = tid >> 6;
  int g = lane >> 4, q = lane & 15;
  long baseQ = (long)b * T_ * 1152 + hh * D_;
  long baseK = baseQ + 384;
  long baseV = baseQ + 768;
  const float scale = 0.20412414523193154f;  // 24^-0.5
  const f32x4 zf = {0.f, 0.f, 0.f, 0.f};

  // zero V pad rows (24..31) once
  for (int i = tid; i < 8 * 136; i += 256) Vts[24 * 136 + i] = 0;
  // stage Q block: 64 rows x 4 chunks of 8
  {
    int r = tid >> 2, c8 = (tid & 3) << 3;
    uint4 val = {0, 0, 0, 0};
    if (c8 < D_) val = *(const uint4*)(qkv + baseQ + (long)(t0 + r) * 1152 + c8);
    *(uint4*)(&Qs[r * 40 + c8]) = val;
  }
  __syncthreads();
  bf16x8 qa = *(const bf16x8*)(&Qs[(w * 16 + q) * 40 + g * 8]);

  f32x4 acc0 = zf, acc1 = zf;
  float lsum[4] = {0.f, 0.f, 0.f, 0.f};

  int send = t0 + 64;
  for (int s0 = 0; s0 < send; s0 += 128) {
    __syncthreads();   // prior iter's LDS reads complete
#pragma unroll
    for (int it = 0; it < 2; ++it) {
      int idx = tid + it * 256;
      int r = idx >> 2, c8 = (idx & 3) << 3;
      uint4 val = {0, 0, 0, 0};
      if (c8 < D_) val = *(const uint4*)(qkv + baseK + (long)(s0 + r) * 1152 + c8);
      *(uint4*)(&Ks[r * 40 + c8]) = val;
      if (c8 < D_) {
        uint4 vv = *(const uint4*)(qkv + baseV + (long)(s0 + r) * 1152 + c8);
        const ushort* pv = (const ushort*)&vv;
#pragma unroll
        for (int e = 0; e < 8; ++e) Vts[(c8 + e) * 136 + r] = pv[e];
      }
    }
    __syncthreads();
    // QK^T: 8 tiles of 16 s; K=32 covers d (pad zeros)
#pragma unroll
    for (int si = 0; si < 8; ++si) {
      bf16x8 kb = *(const bf16x8*)(&Ks[(si * 16 + q) * 40 + g * 8]);
      f32x4 sc = __builtin_amdgcn_mfma_f32_16x16x32_bf16(qa, kb, zf, 0, 0, 0);
      int s_abs = s0 + si * 16 + q;
#pragma unroll
      for (int j = 0; j < 4; ++j) {
        int t_abs = t0 + w * 16 + g * 4 + j;
        float p = (s_abs <= t_abs) ? __expf(sc[j] * scale) : 0.f;
        lsum[j] += p;
        Ps[(w * 16 + g * 4 + j) * 136 + si * 16 + q] = f2b(p);
      }
    }
    __syncthreads();   // P visible to whole wave-group before PV
    // PV: O[t,d] += P[t,s] V[s,d];  A=P contiguous-8, B=Vt contiguous-8
#pragma unroll
    for (int kk = 0; kk < 4; ++kk) {
      bf16x8 pa  = *(const bf16x8*)(&Ps[(w * 16 + q) * 136 + kk * 32 + g * 8]);
      bf16x8 vb0 = *(const bf16x8*)(&Vts[q * 136 + kk * 32 + g * 8]);
      acc0 = __builtin_amdgcn_mfma_f32_16x16x32_bf16(pa, vb0, acc0, 0, 0, 0);
      bf16x8 vb1 = *(const bf16x8*)(&Vts[(16 + q) * 136 + kk * 32 + g * 8]);
      acc1 = __builtin_amdgcn_mfma_f32_16x16x32_bf16(pa, vb1, acc1, 0, 0, 0);
    }
  }
  // finish row sums: reduce over the 16 column-lanes (same g group)
#pragma unroll
  for (int m = 1; m < 16; m <<= 1)
#pragma unroll
    for (int j = 0; j < 4; ++j) lsum[j] += __shfl_xor(lsum[j], m);
  // write O (bf16) into concat layout col h*24+d
#pragma unroll
  for (int j = 0; j < 4; ++j) {
    float inv = 1.f / lsum[j];
    int t_abs = t0 + w * 16 + g * 4 + j;
    long orow = (long)(b * T_ + t_abs) * C_ + hh * D_;
    o[orow + q] = f2b(acc0[j] * inv);
    if (q < 8) o[orow + 16 + q] = f2b(acc1[j] * inv);
  }
}

// ---------------- host side ----------------
extern "C" void kernel_launch(void* const* d_in, const int* in_sizes, int n_in,
                              void* d_out, int out_size, void* d_ws, size_t ws_size,
                              hipStream_t stream) {
  (void)in_sizes; (void)n_in; (void)out_size; (void)ws_size;
  const float* idx  = (const float*)d_in[0];
  const float* pos  = (const float*)d_in[1];
  const float* Wq   = (const float*)d_in[2];
  const float* Wk   = (const float*)d_in[3];
  const float* Wv   = (const float*)d_in[4];
  const float* Wo   = (const float*)d_in[5];
  const float* bo   = (const float*)d_in[6];
  const float* ln1g = (const float*)d_in[7];
  const float* ln1b = (const float*)d_in[8];
  const float* ln2g = (const float*)d_in[9];
  const float* ln2b = (const float*)d_in[10];
  const float* W1   = (const float*)d_in[11];
  const float* b1   = (const float*)d_in[12];
  const float* W2   = (const float*)d_in[13];
  const float* b2   = (const float*)d_in[14];
  const float* lnfg = (const float*)d_in[15];
  const float* lnfb = (const float*)d_in[16];

  char* ws = (char*)d_ws;
  float*  x     = (float*)(ws);                 // 8192*384 f32      = 12,582,912 B
  ushort* h     = (ushort*)(ws + 12582912);     // 8192*384 bf16     =  6,291,456
  ushort* qkv   = (ushort*)(ws + 18874368);     // 8192*1152 bf16    = 18,874,368
  ushort* o     = (ushort*)(ws + 37748736);     // 8192*384 bf16     =  6,291,456
  ushort* u     = (ushort*)(ws + 44040192);     // 8192*1536 bf16    = 25,165,824
  ushort* WqkvT = (ushort*)(ws + 69206016);     // 8*1152*384 bf16   =  7,077,888
  ushort* WoT   = (ushort*)(ws + 76283904);     // 8*384*384 bf16    =  2,359,296
  ushort* W1T   = (ushort*)(ws + 78643200);     // 8*1536*384 bf16   =  9,437,184
  ushort* W2T   = (ushort*)(ws + 88080384);     // 8*384*1536 bf16   =  9,437,184
                                                // total ~93 MB

  // weight prep (bf16, [N][K] output-major for contiguous B-tile vec loads)
  k_trans_qkv<<<dim3(1, 12, L_ * H_), 256, 0, stream>>>(Wq, WqkvT, 0);
  k_trans_qkv<<<dim3(1, 12, L_ * H_), 256, 0, stream>>>(Wk, WqkvT, 1);
  k_trans_qkv<<<dim3(1, 12, L_ * H_), 256, 0, stream>>>(Wv, WqkvT, 2);
  k_trans_w<<<dim3(12, 12, L_), 256, 0, stream>>>(Wo, WoT, C_, C_);
  k_trans_w<<<dim3(48, 12, L_), 256, 0, stream>>>(W1, W1T, C_, F_);
  k_trans_w<<<dim3(12, 48, L_), 256, 0, stream>>>(W2, W2T, F_, C_);

  k_embed<<<(M_ * C_) / (256 * 4), 256, 0, stream>>>(idx, pos, x);

  for (int l = 0; l < L_; ++l) {
    k_ln<<<M_ / 4, 256, 0, stream>>>(x, ln1g + l * C_, ln1b + l * C_, h);
    k_gemm<<<dim3(1152 / 128, M_ / 128), 256, 0, stream>>>(
        h, C_, WqkvT + (long)l * 1152 * C_, C_,
        nullptr, nullptr, nullptr, qkv, 1152, C_, 0);
    k_attn<<<dim3(T_ / 64, B_ * H_), 256, 0, stream>>>(qkv, o);
    k_gemm<<<dim3(C_ / 128, M_ / 128), 256, 0, stream>>>(
        o, C_, WoT + (long)l * C_ * C_, C_,
        bo + l * C_, x, x, nullptr, C_, C_, 0);
    k_ln<<<M_ / 4, 256, 0, stream>>>(x, ln2g + l * C_, ln2b + l * C_, h);
    k_gemm<<<dim3(F_ / 128, M_ / 128), 256, 0, stream>>>(
        h, C_, W1T + (long)l * F_ * C_, C_,
        b1 + l * F_, nullptr, nullptr, u, F_, C_, 1);
    k_gemm<<<dim3(C_ / 128, M_ / 128), 256, 0, stream>>>(
        u, F_, W2T + (long)l * C_ * F_, F_,
        b2 + l * C_, x, x, nullptr, C_, F_, 0);
  }
  k_lnf<<<M_ / 4, 256, 0, stream>>>(x, lnfg, lnfb, (float*)d_out);
}